// Round 10
// baseline (60.062 us; speedup 1.0000x reference)
//
#include <hip/hip_runtime.h>
#include <hip/hip_bf16.h>
#include <math.h>

#define BDIM 4096
#define DDIM 256
#define N2   8192
#define CSPLIT 32            // 32 col slices of 256
#define BROWS 256            // rows per block (4 waves x 64 rows)
#define BN 32                // col tile
#define NT 8                 // tiles per block (256 cols)
#define TILEB (BN * DDIM)    // 8192 bytes per fp8 tile
#define RING 4
#define SCALE1 0x7F7F7F7F    // E8M0 127 = 2^0 in every byte

typedef float f32x4 __attribute__((ext_vector_type(4)));
typedef int   i32x4 __attribute__((ext_vector_type(4)));
typedef int   i32x8 __attribute__((ext_vector_type(8)));

#define WAITVM(N) asm volatile("s_waitcnt vmcnt(" #N ")" ::: "memory")

__device__ __forceinline__ void gload_lds16(const void* g, void* lds) {
    __builtin_amdgcn_global_load_lds(
        (const __attribute__((address_space(1))) unsigned int*)g,
        (__attribute__((address_space(3))) unsigned int*)lds, 16, 0, 0);
}

// ---------------- Kernel 1: L2-normalize rows, emit fp8 reps (natural k-order) + fp32 pos ----------------
__global__ __launch_bounds__(256) void norm_kernel(const float* __restrict__ z1,
                                                   const float* __restrict__ z2,
                                                   unsigned char* __restrict__ reps,
                                                   float* __restrict__ pos) {
    int gwave = (blockIdx.x * 256 + threadIdx.x) >> 6;
    int lane  = threadIdx.x & 63;
    if (gwave >= BDIM) return;

    const float4 a = *(const float4*)&z1[(size_t)gwave * DDIM + lane * 4];
    const float4 b = *(const float4*)&z2[(size_t)gwave * DDIM + lane * 4];

    float s1 = a.x*a.x + a.y*a.y + a.z*a.z + a.w*a.w;
    float s2 = b.x*b.x + b.y*b.y + b.z*b.z + b.w*b.w;
    float d  = a.x*b.x + a.y*b.y + a.z*b.z + a.w*b.w;
    #pragma unroll
    for (int off = 32; off; off >>= 1) {
        s1 += __shfl_xor(s1, off);
        s2 += __shfl_xor(s2, off);
        d  += __shfl_xor(d,  off);
    }
    float r1 = 1.0f / fmaxf(sqrtf(s1), 1e-12f);
    float r2 = 1.0f / fmaxf(sqrtf(s2), 1e-12f);

    int pk1 = __builtin_amdgcn_cvt_pk_fp8_f32(a.x * r1, a.y * r1, 0, false);
    pk1     = __builtin_amdgcn_cvt_pk_fp8_f32(a.z * r1, a.w * r1, pk1, true);
    int pk2 = __builtin_amdgcn_cvt_pk_fp8_f32(b.x * r2, b.y * r2, 0, false);
    pk2     = __builtin_amdgcn_cvt_pk_fp8_f32(b.z * r2, b.w * r2, pk2, true);

    *(int*)(reps + (size_t)gwave * DDIM + lane * 4)          = pk1;
    *(int*)(reps + (size_t)(gwave + BDIM) * DDIM + lane * 4) = pk2;

    if (lane == 0) pos[gwave] = d * r1 * r2;
}

// ---------------- Kernel 2: MX-fp8 GEMM (K=128 scaled MFMA) + exp row sums, 64 rows/wave ----------------
// 1024 blocks (32 rowgroups x 32 colslices) = 4/CU, one round. 4 waves x 64
// rows; A = 64 VGPR/wave. B: 8 KB tiles, 4-buffer LDS ring. Staging obeys the
// global_load_lds constraint (dest = wave-uniform base + lane*16, stride
// EXACTLY 16): each wave issues 2 loads at uniform bases wave*2048 + i*1024,
// XOR-granule-swizzled source (r8-verified conflict-free read pattern).
__global__ __launch_bounds__(256, 4) void lse11_kernel(const unsigned char* __restrict__ reps,
                                                       float* __restrict__ partial) {
    __shared__ __attribute__((aligned(16))) unsigned char Bt[RING * TILEB];  // 32 KB

    const int tid  = threadIdx.x;
    const int wave = tid >> 6;
    const int lane = tid & 63;
    const int l15  = lane & 15;
    const int lq   = lane >> 4;
    const int rg   = blockIdx.x >> 5;
    const int cs   = blockIdx.x & 31;
    const int r0   = rg * BROWS;
    const int col0 = cs * (BN * NT);

    // hoist A fragments: 4 rowgroups x 2 K-halves, 32B/lane (natural k-order)
    i32x8 afr[4][2];
    #pragma unroll
    for (int g = 0; g < 4; ++g) {
        const unsigned char* ap = reps + (size_t)(r0 + wave * 64 + g * 16 + l15) * DDIM + lq * 32;
        #pragma unroll
        for (int m = 0; m < 2; ++m) {
            i32x4 lo = *(const i32x4*)(ap + m * 128);
            i32x4 hi = *(const i32x4*)(ap + m * 128 + 16);
            afr[g][m] = __builtin_shufflevector(lo, hi, 0, 1, 2, 3, 4, 5, 6, 7);
        }
    }

    // per-lane B ds_read byte offsets: logical granule q = m*8+lq*2+h of col
    // l15 sits at physical granule q^l15 (involutive XOR swizzle)
    int qo[2][2];
    #pragma unroll
    for (int m = 0; m < 2; ++m)
        #pragma unroll
        for (int h = 0; h < 2; ++h)
            qo[m][h] = (((m * 8 + lq * 2 + h) ^ l15) << 4);

    // stage: dest D = wave*2048 + i*1024 + lane*16 (lane-stride == 16, legal),
    // source granule = destGranule ^ (tilecol & 15)  [m173 pre-swizzle]
    const unsigned char* sp[2];
    #pragma unroll
    for (int i = 0; i < 2; ++i) {
        int D  = wave * 2048 + i * 1024 + lane * 16;
        int tc = D >> 8;
        int gq = ((D >> 4) & 15) ^ (tc & 15);
        sp[i] = reps + (size_t)(col0 + tc) * DDIM + (gq << 4);
    }

    f32x4 S[4] = {{0.f,0.f,0.f,0.f},{0.f,0.f,0.f,0.f},
                  {0.f,0.f,0.f,0.f},{0.f,0.f,0.f,0.f}};

    auto stage = [&](int buf) {
        #pragma unroll
        for (int i = 0; i < 2; ++i) {
            gload_lds16(sp[i], &Bt[buf * TILEB + wave * 2048 + i * 1024 + lane * 16]);
            sp[i] += BN * DDIM;   // next tile (+8192 B)
        }
    };

    auto compute = [&](int buf) {
        const unsigned char* bb = &Bt[buf * TILEB];
        #pragma unroll
        for (int fg = 0; fg < 2; ++fg) {
            const unsigned char* colp = bb + (fg * 16 + l15) * 256;
            f32x4 acc[4] = {{0.f,0.f,0.f,0.f},{0.f,0.f,0.f,0.f},
                            {0.f,0.f,0.f,0.f},{0.f,0.f,0.f,0.f}};
            __builtin_amdgcn_s_setprio(1);
            #pragma unroll
            for (int m = 0; m < 2; ++m) {
                i32x4 lo = *(const i32x4*)(colp + qo[m][0]);
                i32x4 hi = *(const i32x4*)(colp + qo[m][1]);
                i32x8 bv = __builtin_shufflevector(lo, hi, 0, 1, 2, 3, 4, 5, 6, 7);
                #pragma unroll
                for (int g = 0; g < 4; ++g)
                    acc[g] = __builtin_amdgcn_mfma_scale_f32_16x16x128_f8f6f4(
                                 afr[g][m], bv, acc[g], 0, 0, 0, SCALE1, 0, SCALE1);
            }
            __builtin_amdgcn_s_setprio(0);
            #pragma unroll
            for (int g = 0; g < 4; ++g)
                #pragma unroll
                for (int r = 0; r < 4; ++r)
                    S[g][r] += exp2f(fmaf(acc[g][r], 2.8853900817779268f, -2.8853900817779268f));
        }
    };

    // counted-vmcnt pipeline: RING=4, PD=2, 8 tiles, 2 loads/wave-slot/tile
    stage(0); stage(1);
    #pragma unroll 1
    for (int t = 0; t < NT - 2; ++t) {
        stage((t + 2) & 3);
        WAITVM(4);                      // tile-t loads retired; 4 newer in flight
        __builtin_amdgcn_s_barrier();
        compute(t & 3);
    }
    WAITVM(2); __builtin_amdgcn_s_barrier(); compute((NT - 2) & 3);
    WAITVM(0); __builtin_amdgcn_s_barrier(); compute((NT - 1) & 3);

    // reduce across the 16 column-lanes
    #pragma unroll
    for (int off = 1; off < 16; off <<= 1)
        #pragma unroll
        for (int g = 0; g < 4; ++g)
            #pragma unroll
            for (int r = 0; r < 4; ++r) S[g][r] += __shfl_xor(S[g][r], off);

    if (l15 == 0) {
        #pragma unroll
        for (int g = 0; g < 4; ++g)
            #pragma unroll
            for (int r = 0; r < 4; ++r)
                partial[(size_t)cs * N2 + r0 + wave * 64 + g * 16 + lq * 4 + r] = S[g][r];
    }
}

// ---------------- Kernel 3a: per-row sum of partials, log, per-block sums ----------------
__global__ __launch_bounds__(256) void finish1_kernel(const float* __restrict__ partial,
                                                      float* __restrict__ blocksum) {
    int row = blockIdx.x * 256 + threadIdx.x;
    float s = -1.0f;                     // remove diagonal self-term exp(0)=1
    #pragma unroll
    for (int cc = 0; cc < CSPLIT; ++cc) s += partial[(size_t)cc * N2 + row];
    float v = logf(s);
    #pragma unroll
    for (int off = 32; off; off >>= 1) v += __shfl_xor(v, off);
    __shared__ float ws4[4];
    if ((threadIdx.x & 63) == 0) ws4[threadIdx.x >> 6] = v;
    __syncthreads();
    if (threadIdx.x == 0) blocksum[blockIdx.x] = ws4[0] + ws4[1] + ws4[2] + ws4[3];
}

// ---------------- Kernel 3b: final scalar ----------------
__global__ __launch_bounds__(256) void finish2_kernel(const float* __restrict__ blocksum,
                                                      const float* __restrict__ pos,
                                                      float* __restrict__ out) {
    float v = (threadIdx.x < 32) ? blocksum[threadIdx.x] : 0.f;
    float p = 0.f;
    for (int i = threadIdx.x; i < BDIM; i += 256) p += pos[i];
    float t = v - 4.0f * p;
    #pragma unroll
    for (int off = 32; off; off >>= 1) t += __shfl_xor(t, off);
    __shared__ float ws4[4];
    if ((threadIdx.x & 63) == 0) ws4[threadIdx.x >> 6] = t;
    __syncthreads();
    if (threadIdx.x == 0)
        out[0] = 2.0f + (ws4[0] + ws4[1] + ws4[2] + ws4[3]) / (float)N2;
}

extern "C" void kernel_launch(void* const* d_in, const int* in_sizes, int n_in,
                              void* d_out, int out_size, void* d_ws, size_t ws_size,
                              hipStream_t stream) {
    const float* z1 = (const float*)d_in[0];
    const float* z2 = (const float*)d_in[1];
    float* out = (float*)d_out;

    unsigned char* reps = (unsigned char*)d_ws;                        // 2 MB fp8
    float* partial  = (float*)((char*)d_ws + (size_t)N2 * DDIM);       // 32*8192*4 = 1 MB
    float* pos      = partial + (size_t)CSPLIT * N2;                   // 16 KB
    float* blocksum = pos + BDIM;                                      // 128 B

    norm_kernel<<<BDIM / 4, 256, 0, stream>>>(z1, z2, reps, pos);
    lse11_kernel<<<(N2 / BROWS) * CSPLIT, 256, 0, stream>>>(reps, partial);
    finish1_kernel<<<N2 / 256, 256, 0, stream>>>(partial, blocksum);
    finish2_kernel<<<1, 256, 0, stream>>>(blocksum, pos, out);
}

// Round 11
// 45.196 us; speedup vs baseline: 1.3289x; 1.3289x over previous
//
#include <hip/hip_runtime.h>
#include <hip/hip_bf16.h>
#include <math.h>

#define BDIM 4096
#define DDIM 256
#define N2   8192
#define CSPLIT 32            // 32 col slices of 256
#define BROWS 256            // rows per block (4 waves x 64 rows)
#define BN 32                // col tile
#define NT 8                 // tiles per block (256 cols)
#define TILEB (BN * DDIM)    // 8192 bytes per fp8 tile
#define RING 4
#define SCALE1 0x7F7F7F7F    // E8M0 127 = 2^0 in every byte

typedef float f32x4 __attribute__((ext_vector_type(4)));
typedef int   i32x4 __attribute__((ext_vector_type(4)));
typedef int   i32x8 __attribute__((ext_vector_type(8)));

#define WAITVM(N) asm volatile("s_waitcnt vmcnt(" #N ")" ::: "memory")

__device__ __forceinline__ void gload_lds16(const void* g, void* lds) {
    __builtin_amdgcn_global_load_lds(
        (const __attribute__((address_space(1))) unsigned int*)g,
        (__attribute__((address_space(3))) unsigned int*)lds, 16, 0, 0);
}

// ---------------- Kernel 1: L2-normalize rows, emit fp8 reps (natural k-order) + fp32 pos ----------------
__global__ __launch_bounds__(256) void norm_kernel(const float* __restrict__ z1,
                                                   const float* __restrict__ z2,
                                                   unsigned char* __restrict__ reps,
                                                   float* __restrict__ pos) {
    int gwave = (blockIdx.x * 256 + threadIdx.x) >> 6;
    int lane  = threadIdx.x & 63;
    if (gwave >= BDIM) return;

    const float4 a = *(const float4*)&z1[(size_t)gwave * DDIM + lane * 4];
    const float4 b = *(const float4*)&z2[(size_t)gwave * DDIM + lane * 4];

    float s1 = a.x*a.x + a.y*a.y + a.z*a.z + a.w*a.w;
    float s2 = b.x*b.x + b.y*b.y + b.z*b.z + b.w*b.w;
    float d  = a.x*b.x + a.y*b.y + a.z*b.z + a.w*b.w;
    #pragma unroll
    for (int off = 32; off; off >>= 1) {
        s1 += __shfl_xor(s1, off);
        s2 += __shfl_xor(s2, off);
        d  += __shfl_xor(d,  off);
    }
    float r1 = 1.0f / fmaxf(sqrtf(s1), 1e-12f);
    float r2 = 1.0f / fmaxf(sqrtf(s2), 1e-12f);

    int pk1 = __builtin_amdgcn_cvt_pk_fp8_f32(a.x * r1, a.y * r1, 0, false);
    pk1     = __builtin_amdgcn_cvt_pk_fp8_f32(a.z * r1, a.w * r1, pk1, true);
    int pk2 = __builtin_amdgcn_cvt_pk_fp8_f32(b.x * r2, b.y * r2, 0, false);
    pk2     = __builtin_amdgcn_cvt_pk_fp8_f32(b.z * r2, b.w * r2, pk2, true);

    *(int*)(reps + (size_t)gwave * DDIM + lane * 4)          = pk1;
    *(int*)(reps + (size_t)(gwave + BDIM) * DDIM + lane * 4) = pk2;

    if (lane == 0) pos[gwave] = d * r1 * r2;
}

// ---------------- Kernel 2: MX-fp8 GEMM (K=128 scaled MFMA) + exp row sums, 64 rows/wave ----------------
// 1024 blocks (32 rowgroups x 32 colslices). 4 waves x 64 rows; A = 64 VGPR/
// wave. __launch_bounds__(256,3): 170-reg cap so the ~120-reg live set FITS
// (r10's LB(256,4)=128 cap spilled: WRITE_SIZE 47 MB of scratch). B: 8 KB
// tiles, 4-buffer LDS ring, legal global_load_lds staging (dest = wave-uniform
// base + lane*16), XOR-granule-swizzled source, counted vmcnt, raw barriers.
__global__ __launch_bounds__(256, 3) void lse12_kernel(const unsigned char* __restrict__ reps,
                                                       float* __restrict__ partial) {
    __shared__ __attribute__((aligned(16))) unsigned char Bt[RING * TILEB];  // 32 KB

    const int tid  = threadIdx.x;
    const int wave = tid >> 6;
    const int lane = tid & 63;
    const int l15  = lane & 15;
    const int lq   = lane >> 4;
    const int rg   = blockIdx.x >> 5;
    const int cs   = blockIdx.x & 31;
    const int r0   = rg * BROWS;
    const int col0 = cs * (BN * NT);

    // hoist A fragments: 4 rowgroups x 2 K-halves, 32B/lane (natural k-order)
    i32x8 afr[4][2];
    #pragma unroll
    for (int g = 0; g < 4; ++g) {
        const unsigned char* ap = reps + (size_t)(r0 + wave * 64 + g * 16 + l15) * DDIM + lq * 32;
        #pragma unroll
        for (int m = 0; m < 2; ++m) {
            i32x4 lo = *(const i32x4*)(ap + m * 128);
            i32x4 hi = *(const i32x4*)(ap + m * 128 + 16);
            afr[g][m] = __builtin_shufflevector(lo, hi, 0, 1, 2, 3, 4, 5, 6, 7);
        }
    }

    // per-lane B ds_read byte offsets: logical granule q = m*8+lq*2+h of col
    // l15 sits at physical granule q^l15 (involutive XOR swizzle)
    int qo[2][2];
    #pragma unroll
    for (int m = 0; m < 2; ++m)
        #pragma unroll
        for (int h = 0; h < 2; ++h)
            qo[m][h] = (((m * 8 + lq * 2 + h) ^ l15) << 4);

    // stage: dest D = wave*2048 + i*1024 + lane*16 (lane-stride == 16, legal),
    // source granule = destGranule ^ (tilecol & 15)  [m173 pre-swizzle]
    const unsigned char* sp[2];
    #pragma unroll
    for (int i = 0; i < 2; ++i) {
        int D  = wave * 2048 + i * 1024 + lane * 16;
        int tc = D >> 8;
        int gq = ((D >> 4) & 15) ^ (tc & 15);
        sp[i] = reps + (size_t)(col0 + tc) * DDIM + (gq << 4);
    }

    f32x4 S[4] = {{0.f,0.f,0.f,0.f},{0.f,0.f,0.f,0.f},
                  {0.f,0.f,0.f,0.f},{0.f,0.f,0.f,0.f}};

    auto stage = [&](int buf) {
        #pragma unroll
        for (int i = 0; i < 2; ++i) {
            gload_lds16(sp[i], &Bt[buf * TILEB + wave * 2048 + i * 1024 + lane * 16]);
            sp[i] += BN * DDIM;   // next tile (+8192 B)
        }
    };

    auto compute = [&](int buf) {
        const unsigned char* bb = &Bt[buf * TILEB];
        #pragma unroll
        for (int fg = 0; fg < 2; ++fg) {
            const unsigned char* colp = bb + (fg * 16 + l15) * 256;
            f32x4 acc[4] = {{0.f,0.f,0.f,0.f},{0.f,0.f,0.f,0.f},
                            {0.f,0.f,0.f,0.f},{0.f,0.f,0.f,0.f}};
            __builtin_amdgcn_s_setprio(1);
            #pragma unroll
            for (int m = 0; m < 2; ++m) {
                i32x4 lo = *(const i32x4*)(colp + qo[m][0]);
                i32x4 hi = *(const i32x4*)(colp + qo[m][1]);
                i32x8 bv = __builtin_shufflevector(lo, hi, 0, 1, 2, 3, 4, 5, 6, 7);
                #pragma unroll
                for (int g = 0; g < 4; ++g)
                    acc[g] = __builtin_amdgcn_mfma_scale_f32_16x16x128_f8f6f4(
                                 afr[g][m], bv, acc[g], 0, 0, 0, SCALE1, 0, SCALE1);
            }
            __builtin_amdgcn_s_setprio(0);
            #pragma unroll
            for (int g = 0; g < 4; ++g)
                #pragma unroll
                for (int r = 0; r < 4; ++r)
                    S[g][r] += exp2f(fmaf(acc[g][r], 2.8853900817779268f, -2.8853900817779268f));
        }
    };

    // counted-vmcnt pipeline: RING=4, PD=2, 8 tiles, 2 loads/wave-slot/tile
    stage(0); stage(1);
    #pragma unroll 1
    for (int t = 0; t < NT - 2; ++t) {
        stage((t + 2) & 3);
        WAITVM(4);                      // tile-t loads retired; 4 newer in flight
        __builtin_amdgcn_s_barrier();
        compute(t & 3);
    }
    WAITVM(2); __builtin_amdgcn_s_barrier(); compute((NT - 2) & 3);
    WAITVM(0); __builtin_amdgcn_s_barrier(); compute((NT - 1) & 3);

    // reduce across the 16 column-lanes
    #pragma unroll
    for (int off = 1; off < 16; off <<= 1)
        #pragma unroll
        for (int g = 0; g < 4; ++g)
            #pragma unroll
            for (int r = 0; r < 4; ++r) S[g][r] += __shfl_xor(S[g][r], off);

    if (l15 == 0) {
        #pragma unroll
        for (int g = 0; g < 4; ++g)
            #pragma unroll
            for (int r = 0; r < 4; ++r)
                partial[(size_t)cs * N2 + r0 + wave * 64 + g * 16 + lq * 4 + r] = S[g][r];
    }
}

// ---------------- Kernel 3a: per-row sum of partials, log, per-block sums ----------------
__global__ __launch_bounds__(256) void finish1_kernel(const float* __restrict__ partial,
                                                      float* __restrict__ blocksum) {
    int row = blockIdx.x * 256 + threadIdx.x;
    float s = -1.0f;                     // remove diagonal self-term exp(0)=1
    #pragma unroll
    for (int cc = 0; cc < CSPLIT; ++cc) s += partial[(size_t)cc * N2 + row];
    float v = logf(s);
    #pragma unroll
    for (int off = 32; off; off >>= 1) v += __shfl_xor(v, off);
    __shared__ float ws4[4];
    if ((threadIdx.x & 63) == 0) ws4[threadIdx.x >> 6] = v;
    __syncthreads();
    if (threadIdx.x == 0) blocksum[blockIdx.x] = ws4[0] + ws4[1] + ws4[2] + ws4[3];
}

// ---------------- Kernel 3b: final scalar ----------------
__global__ __launch_bounds__(256) void finish2_kernel(const float* __restrict__ blocksum,
                                                      const float* __restrict__ pos,
                                                      float* __restrict__ out) {
    float v = (threadIdx.x < 32) ? blocksum[threadIdx.x] : 0.f;
    float p = 0.f;
    for (int i = threadIdx.x; i < BDIM; i += 256) p += pos[i];
    float t = v - 4.0f * p;
    #pragma unroll
    for (int off = 32; off; off >>= 1) t += __shfl_xor(t, off);
    __shared__ float ws4[4];
    if ((threadIdx.x & 63) == 0) ws4[threadIdx.x >> 6] = t;
    __syncthreads();
    if (threadIdx.x == 0)
        out[0] = 2.0f + (ws4[0] + ws4[1] + ws4[2] + ws4[3]) / (float)N2;
}

extern "C" void kernel_launch(void* const* d_in, const int* in_sizes, int n_in,
                              void* d_out, int out_size, void* d_ws, size_t ws_size,
                              hipStream_t stream) {
    const float* z1 = (const float*)d_in[0];
    const float* z2 = (const float*)d_in[1];
    float* out = (float*)d_out;

    unsigned char* reps = (unsigned char*)d_ws;                        // 2 MB fp8
    float* partial  = (float*)((char*)d_ws + (size_t)N2 * DDIM);       // 32*8192*4 = 1 MB
    float* pos      = partial + (size_t)CSPLIT * N2;                   // 16 KB
    float* blocksum = pos + BDIM;                                      // 128 B

    norm_kernel<<<BDIM / 4, 256, 0, stream>>>(z1, z2, reps, pos);
    lse12_kernel<<<(N2 / BROWS) * CSPLIT, 256, 0, stream>>>(reps, partial);
    finish1_kernel<<<N2 / 256, 256, 0, stream>>>(partial, blocksum);
    finish2_kernel<<<1, 256, 0, stream>>>(blocksum, pos, out);
}

// Round 12
// 36.468 us; speedup vs baseline: 1.6470x; 1.2393x over previous
//
#include <hip/hip_runtime.h>
#include <hip/hip_bf16.h>
#include <math.h>

#define BDIM 4096
#define DDIM 256
#define N2   8192
#define CSPLIT 16            // 16 col slices of 512
#define BROWS 256            // rows per block (8 waves x 32 rows)
#define BN 32                // col tile
#define NT 16                // tiles per block (512 cols)
#define TILEB (BN * DDIM)    // 8192 bytes per fp8 tile
#define RING 4
#define SCALE1 0x7F7F7F7F    // E8M0 127 = 2^0 in every byte

typedef float f32x4 __attribute__((ext_vector_type(4)));
typedef int   i32x4 __attribute__((ext_vector_type(4)));
typedef int   i32x8 __attribute__((ext_vector_type(8)));

#define WAITVM(N) asm volatile("s_waitcnt vmcnt(" #N ")" ::: "memory")

__device__ __forceinline__ void gload_lds16(const void* g, void* lds) {
    __builtin_amdgcn_global_load_lds(
        (const __attribute__((address_space(1))) unsigned int*)g,
        (__attribute__((address_space(3))) unsigned int*)lds, 16, 0, 0);
}

// ---------------- Kernel 1: L2-normalize rows, emit fp8 reps (natural k-order) + fp32 pos ----------------
__global__ __launch_bounds__(256) void norm_kernel(const float* __restrict__ z1,
                                                   const float* __restrict__ z2,
                                                   unsigned char* __restrict__ reps,
                                                   float* __restrict__ pos) {
    int gwave = (blockIdx.x * 256 + threadIdx.x) >> 6;
    int lane  = threadIdx.x & 63;
    if (gwave >= BDIM) return;

    const float4 a = *(const float4*)&z1[(size_t)gwave * DDIM + lane * 4];
    const float4 b = *(const float4*)&z2[(size_t)gwave * DDIM + lane * 4];

    float s1 = a.x*a.x + a.y*a.y + a.z*a.z + a.w*a.w;
    float s2 = b.x*b.x + b.y*b.y + b.z*b.z + b.w*b.w;
    float d  = a.x*b.x + a.y*b.y + a.z*b.z + a.w*b.w;
    #pragma unroll
    for (int off = 32; off; off >>= 1) {
        s1 += __shfl_xor(s1, off);
        s2 += __shfl_xor(s2, off);
        d  += __shfl_xor(d,  off);
    }
    float r1 = 1.0f / fmaxf(sqrtf(s1), 1e-12f);
    float r2 = 1.0f / fmaxf(sqrtf(s2), 1e-12f);

    int pk1 = __builtin_amdgcn_cvt_pk_fp8_f32(a.x * r1, a.y * r1, 0, false);
    pk1     = __builtin_amdgcn_cvt_pk_fp8_f32(a.z * r1, a.w * r1, pk1, true);
    int pk2 = __builtin_amdgcn_cvt_pk_fp8_f32(b.x * r2, b.y * r2, 0, false);
    pk2     = __builtin_amdgcn_cvt_pk_fp8_f32(b.z * r2, b.w * r2, pk2, true);

    *(int*)(reps + (size_t)gwave * DDIM + lane * 4)          = pk1;
    *(int*)(reps + (size_t)(gwave + BDIM) * DDIM + lane * 4) = pk2;

    if (lane == 0) pos[gwave] = d * r1 * r2;
}

// ---------------- Kernel 2: MX-fp8 GEMM (K=128 scaled MFMA) + exp row sums ----------------
// R8 structure (best measured): 512 blocks (32 rowgroups x 16 colslices) =
// exactly 2/CU, one round. 8 waves x 32 rows, 512 threads. A: 32 VGPR/wave.
// B: 8 KB tiles, 4-buffer LDS ring, legal global_load_lds (dest lane-stride
// 16), XOR-granule source swizzle (0 conflicts), counted vmcnt, raw barriers.
// CHANGE vs R8: exp2f -> __builtin_amdgcn_exp2f (raw v_exp_f32; arg range
// [-5.8, 0] is denormal/overflow-safe) to kill the ocml slow-path VALU.
__global__ __launch_bounds__(512, 4) void lse13_kernel(const unsigned char* __restrict__ reps,
                                                       float* __restrict__ partial) {
    __shared__ __attribute__((aligned(16))) unsigned char Bt[RING * TILEB];  // 32 KB

    const int tid  = threadIdx.x;
    const int wave = tid >> 6;
    const int lane = tid & 63;
    const int l15  = lane & 15;
    const int lq   = lane >> 4;
    const int rg   = blockIdx.x >> 4;
    const int cs   = blockIdx.x & 15;
    const int r0   = rg * BROWS;
    const int col0 = cs * (BN * NT);

    // hoist A fragments: 2 rowgroups x 2 K-halves, 32B/lane (natural k-order)
    i32x8 afr0[2], afr1[2];
    {
        const unsigned char* a0 = reps + (size_t)(r0 + wave * 32 + l15) * DDIM + lq * 32;
        const unsigned char* a1 = a0 + 16 * DDIM;
        #pragma unroll
        for (int m = 0; m < 2; ++m) {
            i32x4 lo0 = *(const i32x4*)(a0 + m * 128);
            i32x4 hi0 = *(const i32x4*)(a0 + m * 128 + 16);
            i32x4 lo1 = *(const i32x4*)(a1 + m * 128);
            i32x4 hi1 = *(const i32x4*)(a1 + m * 128 + 16);
            afr0[m] = __builtin_shufflevector(lo0, hi0, 0, 1, 2, 3, 4, 5, 6, 7);
            afr1[m] = __builtin_shufflevector(lo1, hi1, 0, 1, 2, 3, 4, 5, 6, 7);
        }
    }

    // per-lane B ds_read byte offsets: logical granule q = m*8+lq*2+h of col
    // l15 sits at physical granule q^l15 (involutive XOR swizzle)
    int qo[2][2];
    #pragma unroll
    for (int m = 0; m < 2; ++m)
        #pragma unroll
        for (int h = 0; h < 2; ++h)
            qo[m][h] = (((m * 8 + lq * 2 + h) ^ l15) << 4);

    // stage source pointer: dest D = tid*16 (wave-uniform base + lane*16, legal),
    // source granule = destGranule ^ (tilecol & 15)
    const unsigned char* sp;
    {
        int D  = tid * 16;
        int tc = D >> 8;
        int gq = ((D >> 4) & 15) ^ (tc & 15);
        sp = reps + (size_t)(col0 + tc) * DDIM + (gq << 4);
    }

    f32x4 S0 = {0.f,0.f,0.f,0.f}, S1 = {0.f,0.f,0.f,0.f};

    auto stage = [&](int buf) {
        gload_lds16(sp, &Bt[buf * TILEB + tid * 16]);
        sp += BN * DDIM;   // next tile (+8192 B)
    };

    auto compute = [&](int buf) {
        const unsigned char* bb = &Bt[buf * TILEB];
        #pragma unroll
        for (int fg = 0; fg < 2; ++fg) {
            const unsigned char* colp = bb + (fg * 16 + l15) * 256;
            f32x4 acc0 = {0.f,0.f,0.f,0.f}, acc1 = {0.f,0.f,0.f,0.f};
            __builtin_amdgcn_s_setprio(1);
            #pragma unroll
            for (int m = 0; m < 2; ++m) {
                i32x4 lo = *(const i32x4*)(colp + qo[m][0]);
                i32x4 hi = *(const i32x4*)(colp + qo[m][1]);
                i32x8 bv = __builtin_shufflevector(lo, hi, 0, 1, 2, 3, 4, 5, 6, 7);
                acc0 = __builtin_amdgcn_mfma_scale_f32_16x16x128_f8f6f4(
                           afr0[m], bv, acc0, 0, 0, 0, SCALE1, 0, SCALE1);
                acc1 = __builtin_amdgcn_mfma_scale_f32_16x16x128_f8f6f4(
                           afr1[m], bv, acc1, 0, 0, 0, SCALE1, 0, SCALE1);
            }
            __builtin_amdgcn_s_setprio(0);
            #pragma unroll
            for (int r = 0; r < 4; ++r) {
                S0[r] += __builtin_amdgcn_exp2f(fmaf(acc0[r], 2.8853900817779268f, -2.8853900817779268f));
                S1[r] += __builtin_amdgcn_exp2f(fmaf(acc1[r], 2.8853900817779268f, -2.8853900817779268f));
            }
        }
    };

    // counted-vmcnt pipeline: RING=4, PD=2, 16 tiles, 1 load/wave-slot/tile
    stage(0); stage(1);
    #pragma unroll 1
    for (int t = 0; t < NT - 2; ++t) {
        stage((t + 2) & 3);
        WAITVM(2);                      // tile-t load retired; 2 newer in flight
        __builtin_amdgcn_s_barrier();
        compute(t & 3);
    }
    WAITVM(1); __builtin_amdgcn_s_barrier(); compute((NT - 2) & 3);
    WAITVM(0); __builtin_amdgcn_s_barrier(); compute((NT - 1) & 3);

    // reduce across the 16 column-lanes
    #pragma unroll
    for (int off = 1; off < 16; off <<= 1) {
        #pragma unroll
        for (int r = 0; r < 4; ++r) {
            S0[r] += __shfl_xor(S0[r], off);
            S1[r] += __shfl_xor(S1[r], off);
        }
    }

    if (l15 == 0) {
        #pragma unroll
        for (int r = 0; r < 4; ++r) {
            partial[(size_t)cs * N2 + r0 + wave * 32 + lq * 4 + r]      = S0[r];
            partial[(size_t)cs * N2 + r0 + wave * 32 + 16 + lq * 4 + r] = S1[r];
        }
    }
}

// ---------------- Kernel 3a: per-row sum of partials, log, per-block sums ----------------
__global__ __launch_bounds__(256) void finish1_kernel(const float* __restrict__ partial,
                                                      float* __restrict__ blocksum) {
    int row = blockIdx.x * 256 + threadIdx.x;
    float s = -1.0f;                     // remove diagonal self-term exp(0)=1
    #pragma unroll
    for (int cc = 0; cc < CSPLIT; ++cc) s += partial[(size_t)cc * N2 + row];
    float v = logf(s);
    #pragma unroll
    for (int off = 32; off; off >>= 1) v += __shfl_xor(v, off);
    __shared__ float ws4[4];
    if ((threadIdx.x & 63) == 0) ws4[threadIdx.x >> 6] = v;
    __syncthreads();
    if (threadIdx.x == 0) blocksum[blockIdx.x] = ws4[0] + ws4[1] + ws4[2] + ws4[3];
}

// ---------------- Kernel 3b: final scalar ----------------
__global__ __launch_bounds__(256) void finish2_kernel(const float* __restrict__ blocksum,
                                                      const float* __restrict__ pos,
                                                      float* __restrict__ out) {
    float v = (threadIdx.x < 32) ? blocksum[threadIdx.x] : 0.f;
    float p = 0.f;
    for (int i = threadIdx.x; i < BDIM; i += 256) p += pos[i];
    float t = v - 4.0f * p;
    #pragma unroll
    for (int off = 32; off; off >>= 1) t += __shfl_xor(t, off);
    __shared__ float ws4[4];
    if ((threadIdx.x & 63) == 0) ws4[threadIdx.x >> 6] = t;
    __syncthreads();
    if (threadIdx.x == 0)
        out[0] = 2.0f + (ws4[0] + ws4[1] + ws4[2] + ws4[3]) / (float)N2;
}

extern "C" void kernel_launch(void* const* d_in, const int* in_sizes, int n_in,
                              void* d_out, int out_size, void* d_ws, size_t ws_size,
                              hipStream_t stream) {
    const float* z1 = (const float*)d_in[0];
    const float* z2 = (const float*)d_in[1];
    float* out = (float*)d_out;

    unsigned char* reps = (unsigned char*)d_ws;                        // 2 MB fp8
    float* partial  = (float*)((char*)d_ws + (size_t)N2 * DDIM);       // 16*8192*4 = 512 KB
    float* pos      = partial + (size_t)CSPLIT * N2;                   // 16 KB
    float* blocksum = pos + BDIM;                                      // 128 B

    norm_kernel<<<BDIM / 4, 256, 0, stream>>>(z1, z2, reps, pos);
    lse13_kernel<<<(N2 / BROWS) * CSPLIT, 512, 0, stream>>>(reps, partial);
    finish1_kernel<<<N2 / 256, 256, 0, stream>>>(partial, blocksum);
    finish2_kernel<<<1, 256, 0, stream>>>(blocksum, pos, out);
}